// Round 1
// baseline (129.072 us; speedup 1.0000x reference)
//
#include <hip/hip_runtime.h>
#include <math.h>

// Problem constants
#define NN   768
#define HH   300
#define KD   768

// ---- ws float layout (matrices stored [h][i], 768 i per row) ----
// P:  [2 g][8 ks][320][768] gemm partials  @ 0
// CF_t[320][768] = hx^T                    @ 3932160
// AF_t[320][768] = (hy[perm]+b1)^T         @ 4177920
// RS  [16 jb][768] per-jblock exp-rowsums  @ 4423680
// T0  t0 contributions[768]                @ 4435968
#define P_OFF    0
#define PKS_STR  245760           // 320*768
#define PG_STR   1966080          // 8*PKS_STR
#define CF_OFF   3932160
#define AF_OFF   4177920
#define RS_OFF   4423680
#define T0_OFF   4435968

// ========== K1: both GEMMs, transposed out, fat tile, K-split 8 =============
// P[g][ks][h][i] = sum_{k in slice} W1[h][koff+k] * src[row(i)][k]
// tile 64h x 128i, per-thread 4h x 8i (32 accs), Kc=96, 256 threads.
// grid (6 i, 5 h, 16 = g*8+ks) = 480 blocks.
__global__ __launch_bounds__(256) void k1_gemm(
    const float* __restrict__ x, const float* __restrict__ y,
    const int* __restrict__ perm, const float* __restrict__ W1,
    float* __restrict__ wsf)
{
    const int tid = threadIdx.x;
    const int tx = tid & 15;          // i: {4tx..4tx+3} u {64+4tx..}
    const int ty = tid >> 4;          // h: 4ty..4ty+3
    const int i0 = blockIdx.x * 128;
    const int h0 = blockIdx.y * 64;
    const int g  = blockIdx.z & 1;
    const int ks = blockIdx.z >> 1;
    const int kbeg = ks * 96;

    const float* src = g ? y : x;
    const int koff = g ? KD : 0;

    __shared__ float Xt[32][132];     // Xt[k][i]
    __shared__ float Wt[32][68];      // Wt[k][h]

    float4 acc[4][2];
    #pragma unroll
    for (int r = 0; r < 4; ++r) { acc[r][0] = make_float4(0,0,0,0);
                                  acc[r][1] = make_float4(0,0,0,0); }

    const int kq = (tid & 7) << 2;
    const float* xp[4];
    int xr[4];
    #pragma unroll
    for (int it = 0; it < 4; ++it) {
        int row = ((tid + it*256) >> 3);          // 0..127
        int gr = i0 + row;
        if (g) gr = perm[gr];
        xp[it] = src + (size_t)gr * KD + kbeg + kq;
        xr[it] = row;
    }
    const float* wp[2];
    int wr[2]; bool wv[2];
    #pragma unroll
    for (int it = 0; it < 2; ++it) {
        int hrow = ((tid + it*256) >> 3);         // 0..63
        int hg = h0 + hrow;
        wv[it] = hg < HH;
        wp[it] = W1 + (size_t)(wv[it] ? hg : 0) * (2*KD) + koff + kbeg + kq;
        wr[it] = hrow;
    }

    for (int kb = 0; kb < 96; kb += 32) {
        float4 xv[4], wvv[2];
        #pragma unroll
        for (int it = 0; it < 4; ++it) xv[it] = *(const float4*)(xp[it] + kb);
        #pragma unroll
        for (int it = 0; it < 2; ++it) {
            wvv[it] = *(const float4*)(wp[it] + kb);
            if (!wv[it]) wvv[it] = make_float4(0,0,0,0);
        }
        if (kb) __syncthreads();
        #pragma unroll
        for (int it = 0; it < 4; ++it) {
            Xt[kq+0][xr[it]] = xv[it].x; Xt[kq+1][xr[it]] = xv[it].y;
            Xt[kq+2][xr[it]] = xv[it].z; Xt[kq+3][xr[it]] = xv[it].w;
        }
        #pragma unroll
        for (int it = 0; it < 2; ++it) {
            Wt[kq+0][wr[it]] = wvv[it].x; Wt[kq+1][wr[it]] = wvv[it].y;
            Wt[kq+2][wr[it]] = wvv[it].z; Wt[kq+3][wr[it]] = wvv[it].w;
        }
        __syncthreads();

        #pragma unroll 8
        for (int k = 0; k < 32; ++k) {
            float4 a  = *(const float4*)&Wt[k][4*ty];
            float4 b0 = *(const float4*)&Xt[k][4*tx];
            float4 b1v = *(const float4*)&Xt[k][64 + 4*tx];
            float ar[4] = {a.x, a.y, a.z, a.w};
            #pragma unroll
            for (int r = 0; r < 4; ++r) {
                acc[r][0].x = fmaf(ar[r], b0.x,  acc[r][0].x);
                acc[r][0].y = fmaf(ar[r], b0.y,  acc[r][0].y);
                acc[r][0].z = fmaf(ar[r], b0.z,  acc[r][0].z);
                acc[r][0].w = fmaf(ar[r], b0.w,  acc[r][0].w);
                acc[r][1].x = fmaf(ar[r], b1v.x, acc[r][1].x);
                acc[r][1].y = fmaf(ar[r], b1v.y, acc[r][1].y);
                acc[r][1].z = fmaf(ar[r], b1v.z, acc[r][1].z);
                acc[r][1].w = fmaf(ar[r], b1v.w, acc[r][1].w);
            }
        }
    }

    float* dst = wsf + P_OFF + (size_t)(g*8 + ks) * PKS_STR;
    #pragma unroll
    for (int r = 0; r < 4; ++r) {
        float* rp = dst + (size_t)(h0 + 4*ty + r) * NN + i0;
        *(float4*)(rp + 4*tx)      = acc[r][0];
        *(float4*)(rp + 64 + 4*tx) = acc[r][1];
    }
}

// ===== K1b: sum 8 K-partials -> CF_t/AF_t; A += b1; pad h-rows -> 0 =========
__global__ __launch_bounds__(256) void k1b_combine(
    const float* __restrict__ b1, float* __restrict__ wsf)
{
    int idx = blockIdx.x * 256 + threadIdx.x;   // 480 blocks -> 122880
    int g = idx >= 61440;
    int rem = idx - g * 61440;
    int h = rem / 192;
    int i4 = (rem % 192) * 4;

    float4 o = make_float4(0.f,0.f,0.f,0.f);
    if (h < HH) {
        const float* p = wsf + P_OFF + (size_t)g * PG_STR + (size_t)h * NN + i4;
        #pragma unroll
        for (int ks = 0; ks < 8; ++ks) {
            float4 v = *(const float4*)(p + (size_t)ks * PKS_STR);
            o.x += v.x; o.y += v.y; o.z += v.z; o.w += v.w;
        }
        if (g) {
            float bv = b1[h];
            o.x += bv; o.y += bv; o.z += bv; o.w += bv;
        }
    }
    float* dst = wsf + (g ? AF_OFF : CF_OFF) + (size_t)h * NN + i4;
    *(float4*)dst = o;
}

// ======== K2: pairwise relu-dot, FULL 300-h per tile, fused exp+rowsum ======
// tile 48i x 48j, per-thread 3x3 (strided 16), grid (16 j, 16 i) = 256 blocks
// = exactly 1/CU, perfectly balanced. H staged in 6 LDS chunks of 50,
// register-double-buffered (issue chunk cc+1 global loads before computing
// chunk cc) so L2 latency hides under the ~2700-cyc compute at 1 wave/SIMD.
// Per h per wave: 7 ds_read_b32 (~41 cyc; As is ty-broadcast, Cs is 16
// consecutive banks -> conflict-free) vs 27 VALU (54 cyc) => VALU-bound.
// Emits: RS[jb][i] = sum_j exp(u) over this block's 48 j (deterministic
// 16-partial combine in K3), and t0[i] = softplus(u) on the j==perm[i]
// diagonal (bijection => exactly one writer per row).
__global__ __launch_bounds__(256) void k2_pair(
    const float* __restrict__ wsf, const float* __restrict__ w2,
    const int* __restrict__ perm, const float* __restrict__ b2,
    float* __restrict__ rsO, float* __restrict__ t0c)
{
    const int tid = threadIdx.x;
    const int tx = tid & 15;           // j: {tx, tx+16, tx+32}
    const int ty = tid >> 4;           // i: {ty, ty+16, ty+32}
    const int j0 = blockIdx.x * 48;
    const int i0 = blockIdx.y * 48;

    const float* AF = wsf + AF_OFF;
    const float* CF = wsf + CF_OFF;

    __shared__ float As[50][48];       // As[h][i]  (row 192 B, float4-aligned)
    __shared__ float Cs[50][48];       // Cs[h][j]
    __shared__ float w2s[50];

    // staging slot assignment: 50 rows x 12 float4 = 600 float4 per matrix
    int ho[3], qo[3]; bool val[3];
    #pragma unroll
    for (int s = 0; s < 3; ++s) {
        int e = tid + s * 256;
        val[s] = e < 600;
        ho[s] = e / 12;
        qo[s] = (e % 12) * 4;
    }

    float acc[3][3];
    #pragma unroll
    for (int r = 0; r < 3; ++r)
        #pragma unroll
        for (int c = 0; c < 3; ++c) acc[r][c] = 0.f;

    // prologue: prefetch chunk 0 into registers
    float4 pa[3] = {}, pc[3] = {};
    #pragma unroll
    for (int s = 0; s < 3; ++s) if (val[s]) {
        pa[s] = *(const float4*)(AF + (size_t)ho[s] * NN + i0 + qo[s]);
        pc[s] = *(const float4*)(CF + (size_t)ho[s] * NN + j0 + qo[s]);
    }
    float pw = (tid < 50) ? w2[tid] : 0.f;

    for (int cc = 0; cc < 6; ++cc) {
        if (cc) __syncthreads();       // prior compute done reading LDS
        #pragma unroll
        for (int s = 0; s < 3; ++s) if (val[s]) {
            *(float4*)&As[ho[s]][qo[s]] = pa[s];
            *(float4*)&Cs[ho[s]][qo[s]] = pc[s];
        }
        if (tid < 50) w2s[tid] = pw;
        __syncthreads();

        if (cc < 5) {                  // issue next chunk's loads NOW
            const float* a = AF + (size_t)(cc + 1) * 50 * NN;
            const float* c = CF + (size_t)(cc + 1) * 50 * NN;
            #pragma unroll
            for (int s = 0; s < 3; ++s) if (val[s]) {
                pa[s] = *(const float4*)(a + (size_t)ho[s] * NN + i0 + qo[s]);
                pc[s] = *(const float4*)(c + (size_t)ho[s] * NN + j0 + qo[s]);
            }
            if (tid < 50) pw = w2[(cc + 1) * 50 + tid];
        }

        #pragma unroll 5
        for (int h = 0; h < 50; ++h) {
            float wh = w2s[h];
            float ar[3] = {As[h][ty], As[h][ty + 16], As[h][ty + 32]};
            float cr[3] = {Cs[h][tx], Cs[h][tx + 16], Cs[h][tx + 32]};
            #pragma unroll
            for (int r = 0; r < 3; ++r)
                #pragma unroll
                for (int c = 0; c < 3; ++c)
                    acc[r][c] = fmaf(fmaxf(ar[r] + cr[c], 0.f), wh, acc[r][c]);
        }
    }

    // epilogue: exp + per-row partial sums + diagonal softplus (t0)
    const float b2v = b2[0];
    #pragma unroll
    for (int r = 0; r < 3; ++r) {
        int i = i0 + ty + 16 * r;
        int pj = perm[i];
        float rsum = 0.f;
        #pragma unroll
        for (int c = 0; c < 3; ++c) {
            int j = j0 + tx + 16 * c;
            float u = acc[r][c] + b2v;
            rsum += expf(u);
            if (j == pj)               // exactly one thread chip-wide per row
                t0c[i] = (u > 0.f) ? u + log1pf(expf(-u)) : log1pf(expf(u));
        }
        #pragma unroll
        for (int off = 8; off; off >>= 1)
            rsum += __shfl_xor(rsum, off, 16);
        if (tx == 0) rsO[(size_t)blockIdx.x * NN + i] = rsum;
    }
}

// ================= K3: combine RS partials + final f64 reduction ============
__global__ __launch_bounds__(256) void k3_final(
    const float* __restrict__ wsf, float* __restrict__ out)
{
    const int tid = threadIdx.x;
    const float* rs = wsf + RS_OFF;
    const float* t0 = wsf + T0_OFF;

    double st0 = 0.0, slse = 0.0;
    for (int i = tid; i < NN; i += 256) {
        float s = 0.f;
        #pragma unroll
        for (int jb = 0; jb < 16; ++jb) s += rs[(size_t)jb * NN + i];
        st0  += (double)t0[i];
        slse += log((double)NN + (double)s);
    }
    __shared__ double sa[256], sb[256];
    sa[tid] = st0; sb[tid] = slse;
    __syncthreads();
    for (int s = 128; s > 0; s >>= 1) {
        if (tid < s) { sa[tid] += sa[tid+s]; sb[tid] += sb[tid+s]; }
        __syncthreads();
    }
    if (tid == 0) {
        double lb = sa[0]/(double)NN - (sb[0]/(double)NN - log((double)NN));
        out[0] = (float)lb;
    }
}

extern "C" void kernel_launch(void* const* d_in, const int* in_sizes, int n_in,
                              void* d_out, int out_size, void* d_ws, size_t ws_size,
                              hipStream_t stream) {
    const float* x    = (const float*)d_in[0];
    const float* y    = (const float*)d_in[1];
    const int*   perm = (const int*)  d_in[2];
    const float* W1   = (const float*)d_in[3];
    const float* b1   = (const float*)d_in[4];
    const float* W2   = (const float*)d_in[5];
    const float* b2   = (const float*)d_in[6];
    float* wsf = (float*)d_ws;
    float* out = (float*)d_out;

    k1_gemm    <<<dim3(6,5,16), 256, 0, stream>>>(x, y, perm, W1, wsf);
    k1b_combine<<<480,          256, 0, stream>>>(b1, wsf);
    k2_pair    <<<dim3(16,16),  256, 0, stream>>>(wsf, W2, perm, b2,
                                                  wsf + RS_OFF, wsf + T0_OFF);
    k3_final   <<<1,            256, 0, stream>>>(wsf, out);
}

// Round 2
// 117.370 us; speedup vs baseline: 1.0997x; 1.0997x over previous
//
#include <hip/hip_runtime.h>
#include <math.h>

// Problem constants
#define NN   768
#define HH   300
#define HP   320            // padded hidden dim (multiple of 64)
#define KD   768

// ---- ws float layout (h-matrices stored [i][h], 320 h per row) ----
// P2: [2 g][8 ks][768 i][320 h] gemm partials  @ 0
// CF2 [768][320] = hx  (i-major)               @ 3932160
// AF2 [768][320] = hy[perm]+b1 (i-major)       @ 4177920
// RS  [16 jb][768] per-jblock exp-rowsums      @ 4423680
// T0  t0 contributions[768]                    @ 4435968
#define P_OFF    0
#define PKS_STR  245760           // 768*320
#define PG_STR   1966080          // 8*PKS_STR
#define CF_OFF   3932160
#define AF_OFF   4177920
#define RS_OFF   4423680
#define T0_OFF   4435968

// ========== K1: both GEMMs, transposed-to-[i][h] out, K-split 8 =============
// P2[g][ks][i][h] = sum_{k in slice} W1[h][koff+k] * src[row(i)][k]
// tile 64h x 128i, per-thread 4h x 8i (32 accs), Kc=96, 256 threads.
// grid (6 i, 5 h, 16 = g*8+ks) = 480 blocks.
// Store: per thread 8x float4 along h (h-quad 4ty..4ty+3 contiguous);
// lanes ty=0..3 of a tx-group fill one 64B line -> full-line writes.
__global__ __launch_bounds__(256) void k1_gemm(
    const float* __restrict__ x, const float* __restrict__ y,
    const int* __restrict__ perm, const float* __restrict__ W1,
    float* __restrict__ wsf)
{
    const int tid = threadIdx.x;
    const int tx = tid & 15;          // i: {4tx..4tx+3} u {64+4tx..}
    const int ty = tid >> 4;          // h: 4ty..4ty+3
    const int i0 = blockIdx.x * 128;
    const int h0 = blockIdx.y * 64;
    const int g  = blockIdx.z & 1;
    const int ks = blockIdx.z >> 1;
    const int kbeg = ks * 96;

    const float* src = g ? y : x;
    const int koff = g ? KD : 0;

    __shared__ float Xt[32][132];     // Xt[k][i]
    __shared__ float Wt[32][68];      // Wt[k][h]

    float acc[4][8];
    #pragma unroll
    for (int r = 0; r < 4; ++r)
        #pragma unroll
        for (int cc = 0; cc < 8; ++cc) acc[r][cc] = 0.f;

    const int kq = (tid & 7) << 2;
    const float* xp[4];
    int xr[4];
    #pragma unroll
    for (int it = 0; it < 4; ++it) {
        int row = ((tid + it*256) >> 3);          // 0..127
        int gr = i0 + row;
        if (g) gr = perm[gr];
        xp[it] = src + (size_t)gr * KD + kbeg + kq;
        xr[it] = row;
    }
    const float* wp[2];
    int wr[2]; bool wv[2];
    #pragma unroll
    for (int it = 0; it < 2; ++it) {
        int hrow = ((tid + it*256) >> 3);         // 0..63
        int hg = h0 + hrow;
        wv[it] = hg < HH;
        wp[it] = W1 + (size_t)(wv[it] ? hg : 0) * (2*KD) + koff + kbeg + kq;
        wr[it] = hrow;
    }

    for (int kb = 0; kb < 96; kb += 32) {
        float4 xv[4], wvv[2];
        #pragma unroll
        for (int it = 0; it < 4; ++it) xv[it] = *(const float4*)(xp[it] + kb);
        #pragma unroll
        for (int it = 0; it < 2; ++it) {
            wvv[it] = *(const float4*)(wp[it] + kb);
            if (!wv[it]) wvv[it] = make_float4(0,0,0,0);
        }
        if (kb) __syncthreads();
        #pragma unroll
        for (int it = 0; it < 4; ++it) {
            Xt[kq+0][xr[it]] = xv[it].x; Xt[kq+1][xr[it]] = xv[it].y;
            Xt[kq+2][xr[it]] = xv[it].z; Xt[kq+3][xr[it]] = xv[it].w;
        }
        #pragma unroll
        for (int it = 0; it < 2; ++it) {
            Wt[kq+0][wr[it]] = wvv[it].x; Wt[kq+1][wr[it]] = wvv[it].y;
            Wt[kq+2][wr[it]] = wvv[it].z; Wt[kq+3][wr[it]] = wvv[it].w;
        }
        __syncthreads();

        #pragma unroll 8
        for (int k = 0; k < 32; ++k) {
            float4 a  = *(const float4*)&Wt[k][4*ty];
            float4 b0 = *(const float4*)&Xt[k][4*tx];
            float4 b1v = *(const float4*)&Xt[k][64 + 4*tx];
            float ar[4] = {a.x, a.y, a.z, a.w};
            float br[8] = {b0.x, b0.y, b0.z, b0.w, b1v.x, b1v.y, b1v.z, b1v.w};
            #pragma unroll
            for (int r = 0; r < 4; ++r)
                #pragma unroll
                for (int cc = 0; cc < 8; ++cc)
                    acc[r][cc] = fmaf(ar[r], br[cc], acc[r][cc]);
        }
    }

    float* dst = wsf + P_OFF + (size_t)(g*8 + ks) * PKS_STR;
    #pragma unroll
    for (int cc = 0; cc < 8; ++cc) {
        int i = i0 + ((cc >> 2) ? 64 : 0) + 4*tx + (cc & 3);
        float4 v = make_float4(acc[0][cc], acc[1][cc], acc[2][cc], acc[3][cc]);
        *(float4*)(dst + (size_t)i * HP + h0 + 4*ty) = v;
    }
}

// ===== K1b: sum 8 K-partials -> CF2/AF2 ([i][h]); A += b1 ===================
// Pad rows h>=300 are zero in P2 (k1's wv guard) -> stay zero here.
__global__ __launch_bounds__(256) void k1b_combine(
    const float* __restrict__ b1, float* __restrict__ wsf)
{
    int idx = blockIdx.x * 256 + threadIdx.x;   // 480 blocks -> 122880
    int g = idx >= 61440;
    int rem = idx - g * 61440;
    int i = rem / 80;                 // 0..767
    int h4 = (rem % 80) * 4;          // 0..316

    float4 o = make_float4(0.f,0.f,0.f,0.f);
    const float* p = wsf + P_OFF + (size_t)g * PG_STR + (size_t)i * HP + h4;
    #pragma unroll
    for (int ks = 0; ks < 8; ++ks) {
        float4 v = *(const float4*)(p + (size_t)ks * PKS_STR);
        o.x += v.x; o.y += v.y; o.z += v.z; o.w += v.w;
    }
    if (g && h4 < HH) {               // HH divisible by 4 -> whole quad valid
        float4 bv = *(const float4*)(b1 + h4);
        o.x += bv.x; o.y += bv.y; o.z += bv.z; o.w += bv.w;
    }
    float* dst = wsf + (g ? AF_OFF : CF_OFF) + (size_t)i * HP + h4;
    *(float4*)dst = o;
}

// ======== K2: pairwise relu-dot, FULL 300-h per tile, fused exp+rowsum ======
// tile 48i x 48j, per-thread 3x3 (strided 16), grid (16 j, 16 i) = 256 blocks.
// [i][h] layout => inner loop reads ONE ds_read_b128 = 4 h per tile row/col:
// 7 b128 per 4-h step feed 108 VALU ops (per CU at 4 waves: ~336 LDS cyc vs
// 216 VALU cyc -> near-balanced, vs 557:216 for the scalar-read version).
// LDS stride 156 (mod 32 = 28) -> <=2-way bank aliasing (free).
// Two h-chunks (152 + 148), LDS = 2*48*156*4 + 1216 = 61120 B.
__global__ __launch_bounds__(256) void k2_pair(
    const float* __restrict__ wsf, const float* __restrict__ w2,
    const int* __restrict__ perm, const float* __restrict__ b2,
    float* __restrict__ rsO, float* __restrict__ t0c)
{
    const int tid = threadIdx.x;
    const int tx = tid & 15;           // j: {tx, tx+16, tx+32}
    const int ty = tid >> 4;           // i: {ty, ty+16, ty+32}
    const int j0 = blockIdx.x * 48;
    const int i0 = blockIdx.y * 48;

    const float* AF = wsf + AF_OFF;
    const float* CF = wsf + CF_OFF;

    __shared__ __align__(16) float As[48][156];   // As[i][h-local]
    __shared__ __align__(16) float Cs[48][156];   // Cs[j][h-local]
    __shared__ __align__(16) float w2s[304];

    if (tid < 76) {
        float4 wv = make_float4(0.f,0.f,0.f,0.f);
        if (tid < 75) wv = *(const float4*)(w2 + 4*tid);
        *(float4*)&w2s[4*tid] = wv;
    }

    float acc[3][3];
    #pragma unroll
    for (int r = 0; r < 3; ++r)
        #pragma unroll
        for (int c = 0; c < 3; ++c) acc[r][c] = 0.f;

    #pragma unroll
    for (int ch = 0; ch < 2; ++ch) {
        const int hbeg = ch * 152;
        const int nq = ch ? 37 : 38;   // 38*4 + 37*4 = 300
        if (ch) __syncthreads();       // prior chunk's compute done reading
        for (int e = tid; e < 48 * nq; e += 256) {
            int i = e / nq, q = e % nq;     // nq literal after unroll
            *(float4*)&As[i][4*q] =
                *(const float4*)(AF + (size_t)(i0 + i) * HP + hbeg + 4*q);
            *(float4*)&Cs[i][4*q] =
                *(const float4*)(CF + (size_t)(j0 + i) * HP + hbeg + 4*q);
        }
        __syncthreads();

        #pragma unroll 2
        for (int k = 0; k < nq; ++k) {
            float4 wq = *(const float4*)&w2s[hbeg + 4*k];
            float4 a0 = *(const float4*)&As[ty     ][4*k];
            float4 a1 = *(const float4*)&As[ty + 16][4*k];
            float4 a2 = *(const float4*)&As[ty + 32][4*k];
            float4 c0 = *(const float4*)&Cs[tx     ][4*k];
            float4 c1 = *(const float4*)&Cs[tx + 16][4*k];
            float4 c2 = *(const float4*)&Cs[tx + 32][4*k];
            const float* wp = (const float*)&wq;
            const float* ap0 = (const float*)&a0;
            const float* ap1 = (const float*)&a1;
            const float* ap2 = (const float*)&a2;
            const float* cp0 = (const float*)&c0;
            const float* cp1 = (const float*)&c1;
            const float* cp2 = (const float*)&c2;
            #pragma unroll
            for (int hh = 0; hh < 4; ++hh) {
                float wh = wp[hh];
                float av0 = ap0[hh], av1 = ap1[hh], av2 = ap2[hh];
                float cv0 = cp0[hh], cv1 = cp1[hh], cv2 = cp2[hh];
                acc[0][0] = fmaf(fmaxf(av0 + cv0, 0.f), wh, acc[0][0]);
                acc[0][1] = fmaf(fmaxf(av0 + cv1, 0.f), wh, acc[0][1]);
                acc[0][2] = fmaf(fmaxf(av0 + cv2, 0.f), wh, acc[0][2]);
                acc[1][0] = fmaf(fmaxf(av1 + cv0, 0.f), wh, acc[1][0]);
                acc[1][1] = fmaf(fmaxf(av1 + cv1, 0.f), wh, acc[1][1]);
                acc[1][2] = fmaf(fmaxf(av1 + cv2, 0.f), wh, acc[1][2]);
                acc[2][0] = fmaf(fmaxf(av2 + cv0, 0.f), wh, acc[2][0]);
                acc[2][1] = fmaf(fmaxf(av2 + cv1, 0.f), wh, acc[2][1]);
                acc[2][2] = fmaf(fmaxf(av2 + cv2, 0.f), wh, acc[2][2]);
            }
        }
    }

    // epilogue: exp + per-row partial sums + diagonal softplus (t0)
    const float b2v = b2[0];
    #pragma unroll
    for (int r = 0; r < 3; ++r) {
        int i = i0 + ty + 16 * r;
        int pj = perm[i];
        float rsum = 0.f;
        #pragma unroll
        for (int c = 0; c < 3; ++c) {
            int j = j0 + tx + 16 * c;
            float u = acc[r][c] + b2v;
            rsum += expf(u);
            if (j == pj)               // exactly one thread chip-wide per row
                t0c[i] = (u > 0.f) ? u + log1pf(expf(-u)) : log1pf(expf(u));
        }
        #pragma unroll
        for (int off = 8; off; off >>= 1)
            rsum += __shfl_xor(rsum, off, 16);
        if (tx == 0) rsO[(size_t)blockIdx.x * NN + i] = rsum;
    }
}

// ================= K3: combine RS partials + final f64 reduction ============
__global__ __launch_bounds__(256) void k3_final(
    const float* __restrict__ wsf, float* __restrict__ out)
{
    const int tid = threadIdx.x;
    const float* rs = wsf + RS_OFF;
    const float* t0 = wsf + T0_OFF;

    double st0 = 0.0, slse = 0.0;
    for (int i = tid; i < NN; i += 256) {
        float s = 0.f;
        #pragma unroll
        for (int jb = 0; jb < 16; ++jb) s += rs[(size_t)jb * NN + i];
        st0  += (double)t0[i];
        slse += log((double)NN + (double)s);
    }
    __shared__ double sa[256], sb[256];
    sa[tid] = st0; sb[tid] = slse;
    __syncthreads();
    for (int s = 128; s > 0; s >>= 1) {
        if (tid < s) { sa[tid] += sa[tid+s]; sb[tid] += sb[tid+s]; }
        __syncthreads();
    }
    if (tid == 0) {
        double lb = sa[0]/(double)NN - (sb[0]/(double)NN - log((double)NN));
        out[0] = (float)lb;
    }
}

extern "C" void kernel_launch(void* const* d_in, const int* in_sizes, int n_in,
                              void* d_out, int out_size, void* d_ws, size_t ws_size,
                              hipStream_t stream) {
    const float* x    = (const float*)d_in[0];
    const float* y    = (const float*)d_in[1];
    const int*   perm = (const int*)  d_in[2];
    const float* W1   = (const float*)d_in[3];
    const float* b1   = (const float*)d_in[4];
    const float* W2   = (const float*)d_in[5];
    const float* b2   = (const float*)d_in[6];
    float* wsf = (float*)d_ws;
    float* out = (float*)d_out;

    k1_gemm    <<<dim3(6,5,16), 256, 0, stream>>>(x, y, perm, W1, wsf);
    k1b_combine<<<480,          256, 0, stream>>>(b1, wsf);
    k2_pair    <<<dim3(16,16),  256, 0, stream>>>(wsf, W2, perm, b2,
                                                  wsf + RS_OFF, wsf + T0_OFF);
    k3_final   <<<1,            256, 0, stream>>>(wsf, out);
}

// Round 4
// 115.524 us; speedup vs baseline: 1.1173x; 1.0160x over previous
//
#include <hip/hip_runtime.h>
#include <math.h>

// Problem constants
#define NN   768
#define HH   300
#define HP   320            // padded hidden dim (multiple of 64)
#define KD   768

// ---- ws float layout (h-matrices stored [i][h], 320 h per row) ----
// P2: [2 g][4 ks][768 i][320 h] gemm partials  @ 0
// CF2 [768][320] = hx  (i-major)               @ 1966080
// AF2 [768][320] = hy[perm]+b1 (i-major)       @ 2211840
// RS  [16 jb][768] per-jblock exp-rowsums      @ 2457600
// T0  t0 contributions[768]                    @ 2469888
#define P_OFF    0
#define PKS_STR  245760           // 768*320
#define PG_STR   983040           // 4*PKS_STR
#define CF_OFF   1966080
#define AF_OFF   2211840
#define RS_OFF   2457600
#define T0_OFF   2469888

// ========== K1: both GEMMs, transposed-to-[i][h] out, K-split 4 =============
// P2[g][ks][i][h] = sum_{k in slice} W1[h][koff+k] * src[row(i)][k]
// tile 64h x 128i, per-thread 4h x 8i (32 accs), Kc=192, 256 threads.
// grid (6 i, 5 h, 8 = ks*2+g) = 240 blocks (~1/CU; LDS-pipe-bound either way,
// K-split 4 halves the P2 round-trip k1b pays vs split 8).
__global__ __launch_bounds__(256) void k1_gemm(
    const float* __restrict__ x, const float* __restrict__ y,
    const int* __restrict__ perm, const float* __restrict__ W1,
    float* __restrict__ wsf)
{
    const int tid = threadIdx.x;
    const int tx = tid & 15;          // i: {4tx..} u {64+4tx..}
    const int ty = tid >> 4;          // h: 4ty..4ty+3
    const int i0 = blockIdx.x * 128;
    const int h0 = blockIdx.y * 64;
    const int g  = blockIdx.z & 1;
    const int ks = blockIdx.z >> 1;   // 0..3
    const int kbeg = ks * 192;

    const float* src = g ? y : x;
    const int koff = g ? KD : 0;

    __shared__ float Xt[32][132];     // Xt[k][i]
    __shared__ float Wt[32][68];      // Wt[k][h]

    float acc[4][8];
    #pragma unroll
    for (int r = 0; r < 4; ++r)
        #pragma unroll
        for (int cc = 0; cc < 8; ++cc) acc[r][cc] = 0.f;

    const int kq = (tid & 7) << 2;
    const float* xp[4];
    int xr[4];
    #pragma unroll
    for (int it = 0; it < 4; ++it) {
        int row = ((tid + it*256) >> 3);          // 0..127
        int gr = i0 + row;
        if (g) gr = perm[gr];
        xp[it] = src + (size_t)gr * KD + kbeg + kq;
        xr[it] = row;
    }
    const float* wp[2];
    int wr[2]; bool wv[2];
    #pragma unroll
    for (int it = 0; it < 2; ++it) {
        int hrow = ((tid + it*256) >> 3);         // 0..63
        int hg = h0 + hrow;
        wv[it] = hg < HH;
        wp[it] = W1 + (size_t)(wv[it] ? hg : 0) * (2*KD) + koff + kbeg + kq;
        wr[it] = hrow;
    }

    for (int kb = 0; kb < 192; kb += 32) {
        float4 xv[4], wvv[2];
        #pragma unroll
        for (int it = 0; it < 4; ++it) xv[it] = *(const float4*)(xp[it] + kb);
        #pragma unroll
        for (int it = 0; it < 2; ++it) {
            wvv[it] = *(const float4*)(wp[it] + kb);
            if (!wv[it]) wvv[it] = make_float4(0,0,0,0);
        }
        if (kb) __syncthreads();
        #pragma unroll
        for (int it = 0; it < 4; ++it) {
            Xt[kq+0][xr[it]] = xv[it].x; Xt[kq+1][xr[it]] = xv[it].y;
            Xt[kq+2][xr[it]] = xv[it].z; Xt[kq+3][xr[it]] = xv[it].w;
        }
        #pragma unroll
        for (int it = 0; it < 2; ++it) {
            Wt[kq+0][wr[it]] = wvv[it].x; Wt[kq+1][wr[it]] = wvv[it].y;
            Wt[kq+2][wr[it]] = wvv[it].z; Wt[kq+3][wr[it]] = wvv[it].w;
        }
        __syncthreads();

        #pragma unroll 8
        for (int k = 0; k < 32; ++k) {
            float4 a   = *(const float4*)&Wt[k][4*ty];
            float4 b0  = *(const float4*)&Xt[k][4*tx];
            float4 b1v = *(const float4*)&Xt[k][64 + 4*tx];
            float ar[4] = {a.x, a.y, a.z, a.w};
            float br[8] = {b0.x, b0.y, b0.z, b0.w, b1v.x, b1v.y, b1v.z, b1v.w};
            #pragma unroll
            for (int r = 0; r < 4; ++r)
                #pragma unroll
                for (int cc = 0; cc < 8; ++cc)
                    acc[r][cc] = fmaf(ar[r], br[cc], acc[r][cc]);
        }
    }

    float* dst = wsf + P_OFF + (size_t)(g*4 + ks) * PKS_STR;
    #pragma unroll
    for (int cc = 0; cc < 8; ++cc) {
        int i = i0 + ((cc >> 2) ? 64 : 0) + 4*tx + (cc & 3);
        float4 v = make_float4(acc[0][cc], acc[1][cc], acc[2][cc], acc[3][cc]);
        *(float4*)(dst + (size_t)i * HP + h0 + 4*ty) = v;
    }
}

// ===== K1b: sum 4 K-partials -> CF2/AF2 ([i][h]); A += b1 ===================
// Pad rows h>=300 are zero in P2 (k1's wv guard) -> stay zero here.
__global__ __launch_bounds__(256) void k1b_combine(
    const float* __restrict__ b1, float* __restrict__ wsf)
{
    int idx = blockIdx.x * 256 + threadIdx.x;   // 480 blocks -> 122880
    int g = idx >= 61440;
    int rem = idx - g * 61440;
    int i = rem / 80;                 // 0..767
    int h4 = (rem % 80) * 4;          // 0..316

    float4 o = make_float4(0.f,0.f,0.f,0.f);
    const float* p = wsf + P_OFF + (size_t)g * PG_STR + (size_t)i * HP + h4;
    #pragma unroll
    for (int ks = 0; ks < 4; ++ks) {
        float4 v = *(const float4*)(p + (size_t)ks * PKS_STR);
        o.x += v.x; o.y += v.y; o.z += v.z; o.w += v.w;
    }
    if (g && h4 < HH) {               // HH divisible by 4 -> whole quad valid
        float4 bv = *(const float4*)(b1 + h4);
        o.x += bv.x; o.y += bv.y; o.z += bv.z; o.w += bv.w;
    }
    float* dst = wsf + (g ? AF_OFF : CF_OFF) + (size_t)i * HP + h4;
    *(float4*)dst = o;
}

// ======== K2: pairwise relu-dot, fused exp+rowsum, 512-thr h-split ==========
// tile 48i x 48j, grid (16 j, 16 i) = 256 blocks x 512 threads.
// Intra-block h-split: waves 0-3 do h[0,152), waves 4-7 do h[152,304)
// (pad h>=300 rows of CF/AF are zero => contribute exactly 0). Each half:
// 16tx x 16ty, per-thread 3x3 strided 16, own As/Cs LDS. This gives
// 2 waves/SIMD (vs 1 before) so ds_read latency is hidden by TLP; LDS-pipe
// bound: 38 k-steps x (8 waves x 7 b128 x 12cyc) ~ 10.6 us.
// Halves combined through LDS in fixed order (deterministic), epilogue
// (exp, rowsum, diagonal softplus) by half 0.
__global__ __launch_bounds__(512, 2) void k2_pair(
    const float* __restrict__ wsf, const float* __restrict__ w2,
    const int* __restrict__ perm, const float* __restrict__ b2,
    float* __restrict__ rsO, float* __restrict__ t0c)
{
    const int tid  = threadIdx.x;
    const int half = tid >> 8;         // 0 or 1
    const int t2   = tid & 255;
    const int tx = t2 & 15;            // j: {tx, tx+16, tx+32}
    const int ty = t2 >> 4;            // i: {ty, ty+16, ty+32}
    const int j0 = blockIdx.x * 48;
    const int i0 = blockIdx.y * 48;
    const int hbeg = half * 152;       // 38 quads each; half1 top quad = pad

    const float* AF = wsf + AF_OFF;
    const float* CF = wsf + CF_OFF;

    __shared__ __align__(16) float As[2][48][156];   // [half][i][h-local]
    __shared__ __align__(16) float Cs[2][48][156];   // [half][j][h-local]
    __shared__ __align__(16) float w2s[304];

    if (tid < 76) {
        float4 wv = make_float4(0.f,0.f,0.f,0.f);
        if (tid < 75) wv = *(const float4*)(w2 + 4*tid);
        *(float4*)&w2s[4*tid] = wv;
    }
    // stage (each half stages its own 48 x 38-quad panels, coalesced rows)
    for (int e = t2; e < 48 * 38; e += 256) {
        int i = e / 38, q = e % 38;
        *(float4*)&As[half][i][4*q] =
            *(const float4*)(AF + (size_t)(i0 + i) * HP + hbeg + 4*q);
        *(float4*)&Cs[half][i][4*q] =
            *(const float4*)(CF + (size_t)(j0 + i) * HP + hbeg + 4*q);
    }
    __syncthreads();

    float acc[3][3];
    #pragma unroll
    for (int r = 0; r < 3; ++r)
        #pragma unroll
        for (int c = 0; c < 3; ++c) acc[r][c] = 0.f;

    #pragma unroll 2
    for (int k = 0; k < 38; ++k) {
        float4 wq = *(const float4*)&w2s[hbeg + 4*k];
        float4 a0 = *(const float4*)&As[half][ty     ][4*k];
        float4 a1 = *(const float4*)&As[half][ty + 16][4*k];
        float4 a2 = *(const float4*)&As[half][ty + 32][4*k];
        float4 c0 = *(const float4*)&Cs[half][tx     ][4*k];
        float4 c1 = *(const float4*)&Cs[half][tx + 16][4*k];
        float4 c2 = *(const float4*)&Cs[half][tx + 32][4*k];
        const float* wp  = (const float*)&wq;
        const float* ap0 = (const float*)&a0;
        const float* ap1 = (const float*)&a1;
        const float* ap2 = (const float*)&a2;
        const float* cp0 = (const float*)&c0;
        const float* cp1 = (const float*)&c1;
        const float* cp2 = (const float*)&c2;
        #pragma unroll
        for (int hh = 0; hh < 4; ++hh) {
            float wh = wp[hh];
            float av0 = ap0[hh], av1 = ap1[hh], av2 = ap2[hh];
            float cv0 = cp0[hh], cv1 = cp1[hh], cv2 = cp2[hh];
            acc[0][0] = fmaf(fmaxf(av0 + cv0, 0.f), wh, acc[0][0]);
            acc[0][1] = fmaf(fmaxf(av0 + cv1, 0.f), wh, acc[0][1]);
            acc[0][2] = fmaf(fmaxf(av0 + cv2, 0.f), wh, acc[0][2]);
            acc[1][0] = fmaf(fmaxf(av1 + cv0, 0.f), wh, acc[1][0]);
            acc[1][1] = fmaf(fmaxf(av1 + cv1, 0.f), wh, acc[1][1]);
            acc[1][2] = fmaf(fmaxf(av1 + cv2, 0.f), wh, acc[1][2]);
            acc[2][0] = fmaf(fmaxf(av2 + cv0, 0.f), wh, acc[2][0]);
            acc[2][1] = fmaf(fmaxf(av2 + cv1, 0.f), wh, acc[2][1]);
            acc[2][2] = fmaf(fmaxf(av2 + cv2, 0.f), wh, acc[2][2]);
        }
    }

    // combine halves through LDS (reuse As[0] region; all reads done)
    __syncthreads();
    float* comb = &As[0][0][0];        // [256][9]
    if (half) {
        float* cp = comb + t2 * 9;
        #pragma unroll
        for (int r = 0; r < 3; ++r)
            #pragma unroll
            for (int c = 0; c < 3; ++c) cp[r*3 + c] = acc[r][c];
    }
    __syncthreads();

    if (half == 0) {
        const float* cp = comb + t2 * 9;
        const float b2v = b2[0];
        #pragma unroll
        for (int r = 0; r < 3; ++r) {
            int i = i0 + ty + 16 * r;
            int pj = perm[i];
            float rsum = 0.f;
            #pragma unroll
            for (int c = 0; c < 3; ++c) {
                int j = j0 + tx + 16 * c;
                float u = acc[r][c] + cp[r*3 + c] + b2v;
                rsum += expf(u);
                if (j == pj)           // exactly one thread chip-wide per row
                    t0c[i] = (u > 0.f) ? u + log1pf(expf(-u)) : log1pf(expf(u));
            }
            #pragma unroll
            for (int off = 8; off; off >>= 1)
                rsum += __shfl_xor(rsum, off, 16);
            if (tx == 0) rsO[(size_t)blockIdx.x * NN + i] = rsum;
        }
    }
}

// ================= K3: combine RS partials + final f64 reduction ============
__global__ __launch_bounds__(256) void k3_final(
    const float* __restrict__ wsf, float* __restrict__ out)
{
    const int tid = threadIdx.x;
    const float* rs = wsf + RS_OFF;
    const float* t0 = wsf + T0_OFF;

    double st0 = 0.0, slse = 0.0;
    for (int i = tid; i < NN; i += 256) {
        float s = 0.f;
        #pragma unroll
        for (int jb = 0; jb < 16; ++jb) s += rs[(size_t)jb * NN + i];
        st0  += (double)t0[i];
        slse += log((double)NN + (double)s);
    }
    __shared__ double sa[256], sb[256];
    sa[tid] = st0; sb[tid] = slse;
    __syncthreads();
    for (int s = 128; s > 0; s >>= 1) {
        if (tid < s) { sa[tid] += sa[tid+s]; sb[tid] += sb[tid+s]; }
        __syncthreads();
    }
    if (tid == 0) {
        double lb = sa[0]/(double)NN - (sb[0]/(double)NN - log((double)NN));
        out[0] = (float)lb;
    }
}

extern "C" void kernel_launch(void* const* d_in, const int* in_sizes, int n_in,
                              void* d_out, int out_size, void* d_ws, size_t ws_size,
                              hipStream_t stream) {
    const float* x    = (const float*)d_in[0];
    const float* y    = (const float*)d_in[1];
    const int*   perm = (const int*)  d_in[2];
    const float* W1   = (const float*)d_in[3];
    const float* b1   = (const float*)d_in[4];
    const float* W2   = (const float*)d_in[5];
    const float* b2   = (const float*)d_in[6];
    float* wsf = (float*)d_ws;
    float* out = (float*)d_out;

    k1_gemm    <<<dim3(6,5,8),  256, 0, stream>>>(x, y, perm, W1, wsf);
    k1b_combine<<<480,          256, 0, stream>>>(b1, wsf);
    k2_pair    <<<dim3(16,16),  512, 0, stream>>>(wsf, W2, perm, b2,
                                                  wsf + RS_OFF, wsf + T0_OFF);
    k3_final   <<<1,            256, 0, stream>>>(wsf, out);
}